// Round 1
// baseline (1033.356 us; speedup 1.0000x reference)
//
#include <hip/hip_runtime.h>
#include <hip/hip_bf16.h>
#include <math.h>

#define BATCH 256
#define DMODEL 256
#define NHEAD 8
#define DHEAD 32
#define LP1 257
#define SCALE 0.17677669529663687f  // 1/sqrt(32)

// ---------------- kernel 1: scan lengths -> offsets, valid_off ----------------
__global__ __launch_bounds__(256) void k_scan(const int* __restrict__ lengths,
                                              int* __restrict__ offsets,
                                              int* __restrict__ valid_off) {
    __shared__ int s[BATCH];
    int t = threadIdx.x;
    int v = lengths[t];
    s[t] = v;
    __syncthreads();
    for (int d = 1; d < BATCH; d <<= 1) {
        int add = (t >= d) ? s[t - d] : 0;
        __syncthreads();
        s[t] += add;
        __syncthreads();
    }
    offsets[t]   = s[t] - v;          // exclusive cumsum of lengths
    valid_off[t] = s[t] - v + t;      // packed valid-row base (each batch adds 1 CLS)
}

// ---------------- kernel 2: fill src_idx over packed valid rows ----------------
__global__ __launch_bounds__(256) void k_fill(const int* __restrict__ lengths,
                                              const int* __restrict__ offsets,
                                              const int* __restrict__ valid_off,
                                              int* __restrict__ src_idx) {
    int b = blockIdx.x;
    int len = lengths[b], off = offsets[b], vo = valid_off[b];
    for (int p = threadIdx.x; p < len; p += blockDim.x) src_idx[vo + p] = off + p;
    if (threadIdx.x == 0) src_idx[vo + len] = -1;   // CLS marker
}

// ---------------- kernel 3: packed-row GEMM  [M,256] @ (Wq|Wk) -> Qbuf,Kbuf ----
__global__ __launch_bounds__(256) void k_qk_gemm(const float* __restrict__ x,
                                                 const float* __restrict__ cls_emb,
                                                 const float* __restrict__ Wq,
                                                 const float* __restrict__ Wk,
                                                 const int* __restrict__ src_idx,
                                                 int M,
                                                 float* __restrict__ Qbuf,
                                                 float* __restrict__ Kbuf) {
    int mt = blockIdx.x, nt = blockIdx.y;
    const float* W   = (nt < 4) ? Wq   : Wk;
    float*       Obf = (nt < 4) ? Qbuf : Kbuf;
    int col0 = (nt & 3) * 64;
    int r0   = mt * 64;

    __shared__ float As[64][65];   // [row][k], pad -> conflict-free
    __shared__ float Bs[64][68];   // [k][n], stride 272B (16B aligned rows)

    int t  = threadIdx.x;
    int tx = t & 15, ty = t >> 4;
    float acc[4][4] = {};

    for (int kc = 0; kc < 256; kc += 64) {
        // stage A: 64 rows x 64 k  (coalesced: consecutive lanes -> consecutive k)
        for (int i = t; i < 64 * 64; i += 256) {
            int rl = i >> 6, kl = i & 63;
            int r = r0 + rl;
            float v = 0.f;
            if (r < M) {
                int s = src_idx[r];
                const float* src = (s >= 0) ? (x + (size_t)s * DMODEL) : cls_emb;
                v = src[kc + kl];
            }
            As[rl][kl] = v;
        }
        // stage B: 64 k x 64 n
        for (int i = t; i < 64 * 64; i += 256) {
            int kl = i >> 6, nl = i & 63;
            Bs[kl][nl] = W[(size_t)(kc + kl) * DMODEL + col0 + nl];
        }
        __syncthreads();
        #pragma unroll 16
        for (int kk = 0; kk < 64; ++kk) {
            float a0 = As[ty * 4 + 0][kk];
            float a1 = As[ty * 4 + 1][kk];
            float a2 = As[ty * 4 + 2][kk];
            float a3 = As[ty * 4 + 3][kk];
            float4 bv = *(const float4*)&Bs[kk][tx * 4];
            acc[0][0] += a0 * bv.x; acc[0][1] += a0 * bv.y; acc[0][2] += a0 * bv.z; acc[0][3] += a0 * bv.w;
            acc[1][0] += a1 * bv.x; acc[1][1] += a1 * bv.y; acc[1][2] += a1 * bv.z; acc[1][3] += a1 * bv.w;
            acc[2][0] += a2 * bv.x; acc[2][1] += a2 * bv.y; acc[2][2] += a2 * bv.z; acc[2][3] += a2 * bv.w;
            acc[3][0] += a3 * bv.x; acc[3][1] += a3 * bv.y; acc[3][2] += a3 * bv.z; acc[3][3] += a3 * bv.w;
        }
        __syncthreads();
    }
    for (int i = 0; i < 4; ++i) {
        int r = r0 + ty * 4 + i;
        if (r < M) {
            float4 v = make_float4(acc[i][0], acc[i][1], acc[i][2], acc[i][3]);
            *(float4*)&Obf[(size_t)r * DMODEL + col0 + tx * 4] = v;
        }
    }
}

// ---------------- kernel 4: per-(b,h) softmax + full alpha write ----------------
__global__ __launch_bounds__(256) void k_attn(const float* __restrict__ Qbuf,
                                              const float* __restrict__ Kbuf,
                                              const int* __restrict__ lengths,
                                              const int* __restrict__ valid_off,
                                              float* __restrict__ alpha) {
    int b = blockIdx.x, h = blockIdx.y;
    int len  = lengths[b];
    int base = valid_off[b];
    int L1   = len + 1;

    __shared__ float Qs[LP1][33];
    __shared__ float Ks[LP1][33];
    __shared__ float mrow[LP1];
    __shared__ float srow[LP1];

    int t = threadIdx.x;

    // load Q,K head-slices (rows 0..len)
    for (int i = t; i < L1 * DHEAD; i += 256) {
        int p = i >> 5, d = i & 31;
        size_t g = (size_t)(base + p) * DMODEL + h * DHEAD + d;
        Qs[p][d] = Qbuf[g];
        Ks[p][d] = Kbuf[g];
    }
    __syncthreads();

    // per-row online softmax stats
    for (int xr = t; xr < L1; xr += 256) {
        float q[DHEAD];
        #pragma unroll
        for (int d = 0; d < DHEAD; ++d) q[d] = Qs[xr][d];
        float m = -1e30f, l = 0.f;
        for (int y = 0; y < L1; ++y) {
            float e = 0.f;
            #pragma unroll
            for (int d = 0; d < DHEAD; ++d) e += q[d] * Ks[y][d];
            e *= SCALE;
            float mn = fmaxf(m, e);
            l = l * __expf(m - mn) + __expf(e - mn);
            m = mn;
        }
        mrow[xr] = m;
        srow[xr] = 1.f / l;
    }
    __syncthreads();

    // flat coalesced write of the full 257x257 tile
    float* out = alpha + (size_t)(b * NHEAD + h) * LP1 * LP1;
    const float inv257 = 1.f / 257.f;
    const int tot = LP1 * LP1;
    for (int idx = t; idx < tot; idx += 256) {
        int xr = idx / LP1;
        int y  = idx - xr * LP1;
        float val;
        if (xr > len) {
            val = inv257;                 // fully-masked row -> uniform
        } else if (y > len) {
            val = 0.f;                    // masked key -> exact 0
        } else {
            float e = 0.f;
            #pragma unroll
            for (int d = 0; d < DHEAD; ++d) e += Qs[xr][d] * Ks[y][d];
            val = __expf(e * SCALE - mrow[xr]) * srow[xr];
        }
        out[idx] = val;
    }
}

// ---------------- kernel 5: CLS readout ----------------
__global__ __launch_bounds__(256) void k_out(const float* __restrict__ x,
                                             const float* __restrict__ cls_emb,
                                             const float* __restrict__ Wv,
                                             const float* __restrict__ Wo,
                                             const int* __restrict__ lengths,
                                             const int* __restrict__ offsets,
                                             const float* __restrict__ alpha,
                                             float* __restrict__ cls_out) {
    int b = blockIdx.x, t = threadIdx.x;
    int len = lengths[b], off = offsets[b];

    __shared__ float aw[NHEAD][LP1];
    __shared__ float ctx[NHEAD][DMODEL];
    __shared__ float attnout[DMODEL];

    int L1 = len + 1;
    for (int i = t; i < NHEAD * L1; i += 256) {
        int h = i / L1, y = i - h * L1;
        aw[h][y] = alpha[((size_t)(b * NHEAD + h) * LP1 + len) * LP1 + y];
    }
    __syncthreads();

    // ctx[h][c] = sum_y alpha[h,y] * row_y[c]   (thread owns column c=t)
    float acc[NHEAD] = {};
    for (int y = 0; y < L1; ++y) {
        const float* src = (y < len) ? (x + (size_t)(off + y) * DMODEL) : cls_emb;
        float xv = src[t];
        #pragma unroll
        for (int h = 0; h < NHEAD; ++h) acc[h] += aw[h][y] * xv;
    }
    #pragma unroll
    for (int h = 0; h < NHEAD; ++h) ctx[h][t] = acc[h];
    __syncthreads();

    // attnout[n] = sum_c ctx[h(n)][c] * Wv[c][n]
    {
        int n = t, h = n >> 5;
        float s = 0.f;
        for (int c = 0; c < DMODEL; ++c) s += ctx[h][c] * Wv[(size_t)c * DMODEL + n];
        attnout[n] = s;
    }
    __syncthreads();

    // cls[n] = sum_c attnout[c] * Wo[c][n]
    {
        int n = t;
        float s = 0.f;
        for (int c = 0; c < DMODEL; ++c) s += attnout[c] * Wo[(size_t)c * DMODEL + n];
        cls_out[(size_t)b * DMODEL + n] = s;
    }
}

extern "C" void kernel_launch(void* const* d_in, const int* in_sizes, int n_in,
                              void* d_out, int out_size, void* d_ws, size_t ws_size,
                              hipStream_t stream) {
    const float* x       = (const float*)d_in[0];
    const int*   lengths = (const int*)d_in[1];
    // d_in[2] = max_len (static 256, unused)
    const float* Wq      = (const float*)d_in[3];
    const float* Wk      = (const float*)d_in[4];
    const float* Wv      = (const float*)d_in[5];
    const float* Wo      = (const float*)d_in[6];
    const float* cls_emb = (const float*)d_in[7];

    int total = in_sizes[0] / DMODEL;
    int M = total + BATCH;                 // packed valid rows (tokens + CLS per batch)
    int Mtiles = (M + 63) / 64;

    float* out     = (float*)d_out;
    float* cls_out = out;                        // [256,256]
    float* alpha   = out + BATCH * DMODEL;       // [256,8,257,257]

    char* wsb = (char*)d_ws;
    int* offsets   = (int*)wsb;                  // 256 ints
    int* valid_off = offsets + 256;              // 256 ints
    int* src_idx   = valid_off + 256;            // M ints
    size_t qoff = 2048 + (((size_t)M * 4 + 255) / 256) * 256;
    float* Qbuf = (float*)(wsb + qoff);
    size_t qsz  = (size_t)Mtiles * 64 * DMODEL * sizeof(float);
    float* Kbuf = (float*)(wsb + qoff + qsz);

    k_scan<<<1, 256, 0, stream>>>(lengths, offsets, valid_off);
    k_fill<<<BATCH, 256, 0, stream>>>(lengths, offsets, valid_off, src_idx);

    dim3 g2(Mtiles, 8);
    k_qk_gemm<<<g2, 256, 0, stream>>>(x, cls_emb, Wq, Wk, src_idx, M, Qbuf, Kbuf);

    dim3 g3(BATCH, NHEAD);
    k_attn<<<g3, 256, 0, stream>>>(Qbuf, Kbuf, lengths, valid_off, alpha);

    k_out<<<BATCH, 256, 0, stream>>>(x, cls_emb, Wv, Wo, lengths, offsets, alpha, cls_out);
}

// Round 2
// 915.938 us; speedup vs baseline: 1.1282x; 1.1282x over previous
//
#include <hip/hip_runtime.h>
#include <hip/hip_bf16.h>
#include <math.h>

#define BATCH 256
#define DMODEL 256
#define NHEAD 8
#define DHEAD 32
#define LP1 257
#define SCALE 0.17677669529663687f  // 1/sqrt(32)

// ---------------- kernel 1: scan lengths -> offsets, valid_off ----------------
__global__ __launch_bounds__(256) void k_scan(const int* __restrict__ lengths,
                                              int* __restrict__ offsets,
                                              int* __restrict__ valid_off) {
    __shared__ int s[BATCH];
    int t = threadIdx.x;
    int v = lengths[t];
    s[t] = v;
    __syncthreads();
    for (int d = 1; d < BATCH; d <<= 1) {
        int add = (t >= d) ? s[t - d] : 0;
        __syncthreads();
        s[t] += add;
        __syncthreads();
    }
    offsets[t]   = s[t] - v;          // exclusive cumsum of lengths
    valid_off[t] = s[t] - v + t;      // packed valid-row base (each batch adds 1 CLS)
}

// ---------------- kernel 2: fill src_idx over packed valid rows ----------------
__global__ __launch_bounds__(256) void k_fill(const int* __restrict__ lengths,
                                              const int* __restrict__ offsets,
                                              const int* __restrict__ valid_off,
                                              int* __restrict__ src_idx) {
    int b = blockIdx.x;
    int len = lengths[b], off = offsets[b], vo = valid_off[b];
    for (int p = threadIdx.x; p < len; p += blockDim.x) src_idx[vo + p] = off + p;
    if (threadIdx.x == 0) src_idx[vo + len] = -1;   // CLS marker
}

// ---------------- kernel 3: packed-row GEMM  [M,256] @ (Wq|Wk) -> Qbuf,Kbuf ----
__global__ __launch_bounds__(256) void k_qk_gemm(const float* __restrict__ x,
                                                 const float* __restrict__ cls_emb,
                                                 const float* __restrict__ Wq,
                                                 const float* __restrict__ Wk,
                                                 const int* __restrict__ src_idx,
                                                 int M,
                                                 float* __restrict__ Qbuf,
                                                 float* __restrict__ Kbuf) {
    int mt = blockIdx.x, nt = blockIdx.y;
    const float* W   = (nt < 4) ? Wq   : Wk;
    float*       Obf = (nt < 4) ? Qbuf : Kbuf;
    int col0 = (nt & 3) * 64;
    int r0   = mt * 64;

    __shared__ float As[64][65];
    __shared__ float Bs[64][68];

    int t  = threadIdx.x;
    int tx = t & 15, ty = t >> 4;
    float acc[4][4] = {};

    for (int kc = 0; kc < 256; kc += 64) {
        for (int i = t; i < 64 * 64; i += 256) {
            int rl = i >> 6, kl = i & 63;
            int r = r0 + rl;
            float v = 0.f;
            if (r < M) {
                int s = src_idx[r];
                const float* src = (s >= 0) ? (x + (size_t)s * DMODEL) : cls_emb;
                v = src[kc + kl];
            }
            As[rl][kl] = v;
        }
        for (int i = t; i < 64 * 64; i += 256) {
            int kl = i >> 6, nl = i & 63;
            Bs[kl][nl] = W[(size_t)(kc + kl) * DMODEL + col0 + nl];
        }
        __syncthreads();
        #pragma unroll 16
        for (int kk = 0; kk < 64; ++kk) {
            float a0 = As[ty * 4 + 0][kk];
            float a1 = As[ty * 4 + 1][kk];
            float a2 = As[ty * 4 + 2][kk];
            float a3 = As[ty * 4 + 3][kk];
            float4 bv = *(const float4*)&Bs[kk][tx * 4];
            acc[0][0] += a0 * bv.x; acc[0][1] += a0 * bv.y; acc[0][2] += a0 * bv.z; acc[0][3] += a0 * bv.w;
            acc[1][0] += a1 * bv.x; acc[1][1] += a1 * bv.y; acc[1][2] += a1 * bv.z; acc[1][3] += a1 * bv.w;
            acc[2][0] += a2 * bv.x; acc[2][1] += a2 * bv.y; acc[2][2] += a2 * bv.z; acc[2][3] += a2 * bv.w;
            acc[3][0] += a3 * bv.x; acc[3][1] += a3 * bv.y; acc[3][2] += a3 * bv.z; acc[3][3] += a3 * bv.w;
        }
        __syncthreads();
    }
    for (int i = 0; i < 4; ++i) {
        int r = r0 + ty * 4 + i;
        if (r < M) {
            float4 v = make_float4(acc[i][0], acc[i][1], acc[i][2], acc[i][3]);
            *(float4*)&Obf[(size_t)r * DMODEL + col0 + tx * 4] = v;
        }
    }
}

// ---------------- kernel 4: per-(b,h) softmax + full alpha write ----------------
// Stats pass: lane owns a ROW, q in VGPRs, K broadcast from LDS (b128).
// Write pass: lane owns a COLUMN, K[lane] in VGPRs, q wave-uniform (scalar loads).
__global__ __launch_bounds__(256) void k_attn(const float* __restrict__ Qbuf,
                                              const float* __restrict__ Kbuf,
                                              const int* __restrict__ lengths,
                                              const int* __restrict__ valid_off,
                                              float* __restrict__ alpha) {
    int b = blockIdx.x, h = blockIdx.y;
    int len  = lengths[b];
    int base = valid_off[b];
    int L1   = len + 1;
    int t    = threadIdx.x;

    __shared__ float Ks[LP1][36];    // stride 36 floats = 144B (16B-aligned rows)
    __shared__ float mrow[LP1];
    __shared__ float srow[LP1];

    float* out = alpha + (size_t)(b * NHEAD + h) * LP1 * LP1;
    const float inv257 = 1.f / 257.f;

    // ---- load K head-slice rows 0..len into LDS ----
    for (int i = t; i < L1 * DHEAD; i += 256) {
        int p = i >> 5, d = i & 31;
        Ks[p][d] = Kbuf[(size_t)(base + p) * DMODEL + h * DHEAD + d];
    }
    __syncthreads();

    // ---- stats pass: lane t handles row t (t <= len) ----
    if (t < L1) {
        const float* qrow = Qbuf + (size_t)(base + t) * DMODEL + h * DHEAD;
        float q[DHEAD];
        #pragma unroll
        for (int d4 = 0; d4 < 8; ++d4) {
            float4 v = *(const float4*)&qrow[d4 * 4];
            q[d4*4+0] = v.x; q[d4*4+1] = v.y; q[d4*4+2] = v.z; q[d4*4+3] = v.w;
        }
        float m = -1e30f, l = 0.f;
        for (int y = 0; y < L1; ++y) {
            float e = 0.f;
            #pragma unroll
            for (int d4 = 0; d4 < 8; ++d4) {
                float4 kv = *(const float4*)&Ks[y][d4 * 4];
                e += q[d4*4+0]*kv.x + q[d4*4+1]*kv.y + q[d4*4+2]*kv.z + q[d4*4+3]*kv.w;
            }
            e *= SCALE;
            float mn = fmaxf(m, e);
            l = l * __expf(m - mn) + __expf(e - mn);
            m = mn;
        }
        mrow[t] = m;
        srow[t] = 1.f / l;
    }

    // ---- row 256 stats (only when len==256): one wave, cooperative ----
    if (len == 256 && t < 64) {
        const float* qrow = Qbuf + (size_t)(base + 256) * DMODEL + h * DHEAD;
        float q[DHEAD];
        #pragma unroll
        for (int d4 = 0; d4 < 8; ++d4) {
            float4 v = *(const float4*)&qrow[d4 * 4];
            q[d4*4+0] = v.x; q[d4*4+1] = v.y; q[d4*4+2] = v.z; q[d4*4+3] = v.w;
        }
        float m = -1e30f, l = 0.f;
        for (int y = t; y < 257; y += 64) {
            float e = 0.f;
            #pragma unroll
            for (int d4 = 0; d4 < 8; ++d4) {
                float4 kv = *(const float4*)&Ks[y][d4 * 4];
                e += q[d4*4+0]*kv.x + q[d4*4+1]*kv.y + q[d4*4+2]*kv.z + q[d4*4+3]*kv.w;
            }
            e *= SCALE;
            float mn = fmaxf(m, e);
            l = l * __expf(m - mn) + __expf(e - mn);
            m = mn;
        }
        #pragma unroll
        for (int off = 32; off; off >>= 1) {
            float m2 = __shfl_xor(m, off);
            float l2 = __shfl_xor(l, off);
            float mn = fmaxf(m, m2);
            l = l * __expf(m - mn) + l2 * __expf(m2 - mn);
            m = mn;
        }
        if (t == 0) { mrow[256] = m; srow[256] = 1.f / l; }
    }
    __syncthreads();

    // ---- write pass ----
    int wbase = t & ~63;
    if (wbase > len) {
        // whole wave's columns are masked -> store zeros only
        for (int xr = 0; xr < L1; ++xr)
            out[(size_t)xr * LP1 + t] = 0.f;
    } else {
        // lane's K column into registers
        float k[DHEAD];
        #pragma unroll
        for (int d4 = 0; d4 < 8; ++d4) {
            float4 kv = *(const float4*)&Ks[t][d4 * 4];
            k[d4*4+0] = kv.x; k[d4*4+1] = kv.y; k[d4*4+2] = kv.z; k[d4*4+3] = kv.w;
        }
        bool lane_ok = (t < L1);
        for (int xr = 0; xr < L1; ++xr) {
            const float* qrow = Qbuf + (size_t)(base + xr) * DMODEL + h * DHEAD;  // wave-uniform
            float e = 0.f;
            #pragma unroll
            for (int d4 = 0; d4 < 8; ++d4) {
                float4 qv = *(const float4*)&qrow[d4 * 4];
                e += k[d4*4+0]*qv.x + k[d4*4+1]*qv.y + k[d4*4+2]*qv.z + k[d4*4+3]*qv.w;
            }
            float val = lane_ok ? __expf(e * SCALE - mrow[xr]) * srow[xr] : 0.f;
            out[(size_t)xr * LP1 + t] = val;
            if (t == 0 && len < 256) out[(size_t)xr * LP1 + 256] = 0.f;
        }
    }

    // ---- masked rows: uniform 1/257, flat coalesced ----
    {
        size_t tot = (size_t)LP1 * LP1;
        for (size_t i = (size_t)L1 * LP1 + t; i < tot; i += 256) out[i] = inv257;
    }

    // ---- column 256 (only when len==256) ----
    if (len == 256) {
        float kc[DHEAD];
        #pragma unroll
        for (int d4 = 0; d4 < 8; ++d4) {
            float4 kv = *(const float4*)&Ks[256][d4 * 4];
            kc[d4*4+0] = kv.x; kc[d4*4+1] = kv.y; kc[d4*4+2] = kv.z; kc[d4*4+3] = kv.w;
        }
        for (int xr = t; xr < 257; xr += 256) {
            const float* qrow = Qbuf + (size_t)(base + xr) * DMODEL + h * DHEAD;  // per-lane
            float e = 0.f;
            #pragma unroll
            for (int d4 = 0; d4 < 8; ++d4) {
                float4 qv = *(const float4*)&qrow[d4 * 4];
                e += kc[d4*4+0]*qv.x + kc[d4*4+1]*qv.y + kc[d4*4+2]*qv.z + kc[d4*4+3]*qv.w;
            }
            out[(size_t)xr * LP1 + 256] = __expf(e * SCALE - mrow[xr]) * srow[xr];
        }
    }
}

// ---------------- kernel 5: CLS readout ----------------
__global__ __launch_bounds__(256) void k_out(const float* __restrict__ x,
                                             const float* __restrict__ cls_emb,
                                             const float* __restrict__ Wv,
                                             const float* __restrict__ Wo,
                                             const int* __restrict__ lengths,
                                             const int* __restrict__ offsets,
                                             const float* __restrict__ alpha,
                                             float* __restrict__ cls_out) {
    int b = blockIdx.x, t = threadIdx.x;
    int len = lengths[b], off = offsets[b];

    __shared__ float aw[NHEAD][LP1];
    __shared__ float ctx[NHEAD][DMODEL];
    __shared__ float attnout[DMODEL];

    int L1 = len + 1;
    for (int i = t; i < NHEAD * L1; i += 256) {
        int h = i / L1, y = i - h * L1;
        aw[h][y] = alpha[((size_t)(b * NHEAD + h) * LP1 + len) * LP1 + y];
    }
    __syncthreads();

    float acc[NHEAD] = {};
    for (int y = 0; y < L1; ++y) {
        const float* src = (y < len) ? (x + (size_t)(off + y) * DMODEL) : cls_emb;
        float xv = src[t];
        #pragma unroll
        for (int h = 0; h < NHEAD; ++h) acc[h] += aw[h][y] * xv;
    }
    #pragma unroll
    for (int h = 0; h < NHEAD; ++h) ctx[h][t] = acc[h];
    __syncthreads();

    {
        int n = t, h = n >> 5;
        float s = 0.f;
        for (int c = 0; c < DMODEL; ++c) s += ctx[h][c] * Wv[(size_t)c * DMODEL + n];
        attnout[n] = s;
    }
    __syncthreads();

    {
        int n = t;
        float s = 0.f;
        for (int c = 0; c < DMODEL; ++c) s += attnout[c] * Wo[(size_t)c * DMODEL + n];
        cls_out[(size_t)b * DMODEL + n] = s;
    }
}

extern "C" void kernel_launch(void* const* d_in, const int* in_sizes, int n_in,
                              void* d_out, int out_size, void* d_ws, size_t ws_size,
                              hipStream_t stream) {
    const float* x       = (const float*)d_in[0];
    const int*   lengths = (const int*)d_in[1];
    const float* Wq      = (const float*)d_in[3];
    const float* Wk      = (const float*)d_in[4];
    const float* Wv      = (const float*)d_in[5];
    const float* Wo      = (const float*)d_in[6];
    const float* cls_emb = (const float*)d_in[7];

    int total = in_sizes[0] / DMODEL;
    int M = total + BATCH;
    int Mtiles = (M + 63) / 64;

    float* out     = (float*)d_out;
    float* cls_out = out;                        // [256,256]
    float* alpha   = out + BATCH * DMODEL;       // [256,8,257,257]

    char* wsb = (char*)d_ws;
    int* offsets   = (int*)wsb;
    int* valid_off = offsets + 256;
    int* src_idx   = valid_off + 256;
    size_t qoff = 2048 + (((size_t)M * 4 + 255) / 256) * 256;
    float* Qbuf = (float*)(wsb + qoff);
    size_t qsz  = (size_t)Mtiles * 64 * DMODEL * sizeof(float);
    float* Kbuf = (float*)(wsb + qoff + qsz);

    k_scan<<<1, 256, 0, stream>>>(lengths, offsets, valid_off);
    k_fill<<<BATCH, 256, 0, stream>>>(lengths, offsets, valid_off, src_idx);

    dim3 g2(Mtiles, 8);
    k_qk_gemm<<<g2, 256, 0, stream>>>(x, cls_emb, Wq, Wk, src_idx, M, Qbuf, Kbuf);

    dim3 g3(BATCH, NHEAD);
    k_attn<<<g3, 256, 0, stream>>>(Qbuf, Kbuf, lengths, valid_off, alpha);

    k_out<<<BATCH, 256, 0, stream>>>(x, cls_emb, Wv, Wo, lengths, offsets, alpha, cls_out);
}

// Round 3
// 678.779 us; speedup vs baseline: 1.5224x; 1.3494x over previous
//
#include <hip/hip_runtime.h>
#include <hip/hip_bf16.h>
#include <math.h>

#define BATCH 256
#define DMODEL 256
#define NHEAD 8
#define DHEAD 32
#define LP1 257
#define SCALE 0.17677669529663687f  // 1/sqrt(32)

// ---------------- kernel 1: scan lengths -> offsets, valid_off ----------------
__global__ __launch_bounds__(256) void k_scan(const int* __restrict__ lengths,
                                              int* __restrict__ offsets,
                                              int* __restrict__ valid_off) {
    __shared__ int s[BATCH];
    int t = threadIdx.x;
    int v = lengths[t];
    s[t] = v;
    __syncthreads();
    for (int d = 1; d < BATCH; d <<= 1) {
        int add = (t >= d) ? s[t - d] : 0;
        __syncthreads();
        s[t] += add;
        __syncthreads();
    }
    offsets[t]   = s[t] - v;          // exclusive cumsum of lengths
    valid_off[t] = s[t] - v + t;      // packed valid-row base (each batch adds 1 CLS)
}

// ---------------- kernel 2: fill src_idx over packed valid rows ----------------
__global__ __launch_bounds__(256) void k_fill(const int* __restrict__ lengths,
                                              const int* __restrict__ offsets,
                                              const int* __restrict__ valid_off,
                                              int* __restrict__ src_idx) {
    int b = blockIdx.x;
    int len = lengths[b], off = offsets[b], vo = valid_off[b];
    for (int p = threadIdx.x; p < len; p += blockDim.x) src_idx[vo + p] = off + p;
    if (threadIdx.x == 0) src_idx[vo + len] = -1;   // CLS marker
}

// ---------------- kernel 3: packed-row GEMM  [M,256] @ (Wq|Wk) -> Qbuf,Kbuf ----
__global__ __launch_bounds__(256) void k_qk_gemm(const float* __restrict__ x,
                                                 const float* __restrict__ cls_emb,
                                                 const float* __restrict__ Wq,
                                                 const float* __restrict__ Wk,
                                                 const int* __restrict__ src_idx,
                                                 int M,
                                                 float* __restrict__ Qbuf,
                                                 float* __restrict__ Kbuf) {
    int mt = blockIdx.x, nt = blockIdx.y;
    const float* W   = (nt < 4) ? Wq   : Wk;
    float*       Obf = (nt < 4) ? Qbuf : Kbuf;
    int col0 = (nt & 3) * 64;
    int r0   = mt * 64;

    __shared__ float As[64][65];
    __shared__ float Bs[64][68];

    int t  = threadIdx.x;
    int tx = t & 15, ty = t >> 4;
    float acc[4][4] = {};

    for (int kc = 0; kc < 256; kc += 64) {
        for (int i = t; i < 64 * 64; i += 256) {
            int rl = i >> 6, kl = i & 63;
            int r = r0 + rl;
            float v = 0.f;
            if (r < M) {
                int s = src_idx[r];
                const float* src = (s >= 0) ? (x + (size_t)s * DMODEL) : cls_emb;
                v = src[kc + kl];
            }
            As[rl][kl] = v;
        }
        for (int i = t; i < 64 * 64; i += 256) {
            int kl = i >> 6, nl = i & 63;
            Bs[kl][nl] = W[(size_t)(kc + kl) * DMODEL + col0 + nl];
        }
        __syncthreads();
        #pragma unroll 16
        for (int kk = 0; kk < 64; ++kk) {
            float a0 = As[ty * 4 + 0][kk];
            float a1 = As[ty * 4 + 1][kk];
            float a2 = As[ty * 4 + 2][kk];
            float a3 = As[ty * 4 + 3][kk];
            float4 bv = *(const float4*)&Bs[kk][tx * 4];
            acc[0][0] += a0 * bv.x; acc[0][1] += a0 * bv.y; acc[0][2] += a0 * bv.z; acc[0][3] += a0 * bv.w;
            acc[1][0] += a1 * bv.x; acc[1][1] += a1 * bv.y; acc[1][2] += a1 * bv.z; acc[1][3] += a1 * bv.w;
            acc[2][0] += a2 * bv.x; acc[2][1] += a2 * bv.y; acc[2][2] += a2 * bv.z; acc[2][3] += a2 * bv.w;
            acc[3][0] += a3 * bv.x; acc[3][1] += a3 * bv.y; acc[3][2] += a3 * bv.z; acc[3][3] += a3 * bv.w;
        }
        __syncthreads();
    }
    for (int i = 0; i < 4; ++i) {
        int r = r0 + ty * 4 + i;
        if (r < M) {
            float4 v = make_float4(acc[i][0], acc[i][1], acc[i][2], acc[i][3]);
            *(float4*)&Obf[(size_t)r * DMODEL + col0 + tx * 4] = v;
        }
    }
}

// ---------------- kernel 4: per-(b,h) attention, single pass ----------------
// Wave owns a row; lane owns 4 fixed K-columns in VGPRs (cols l, l+64, l+128, l+192).
// Per row: uniform q loads (cache-broadcast), 4 dots, butterfly max+sum allreduce,
// normalize in-register, coalesced stores. Every element computed exactly once.
__global__ __launch_bounds__(256, 2) void k_attn(const float* __restrict__ Qbuf,
                                                 const float* __restrict__ Kbuf,
                                                 const int* __restrict__ lengths,
                                                 const int* __restrict__ valid_off,
                                                 float* __restrict__ alpha) {
    int b = blockIdx.x, h = blockIdx.y;
    int len  = __builtin_amdgcn_readfirstlane(lengths[b]);
    int base = __builtin_amdgcn_readfirstlane(valid_off[b]);
    int t = threadIdx.x;
    int l = t & 63;          // lane within wave
    int w = t >> 6;          // wave id (0..3)
    float* out = alpha + (size_t)(b * NHEAD + h) * (size_t)(LP1 * LP1);

    // --- load this lane's 4 K columns into registers ---
    float4 kc[4][8];
    #pragma unroll
    for (int j = 0; j < 4; ++j) {
        #pragma unroll
        for (int d = 0; d < 8; ++d) kc[j][d] = make_float4(0.f, 0.f, 0.f, 0.f);
        int c = l + 64 * j;
        if (c <= len) {
            const float* kp = Kbuf + (size_t)(base + c) * DMODEL + h * DHEAD;
            #pragma unroll
            for (int d = 0; d < 8; ++d) kc[j][d] = *(const float4*)&kp[d * 4];
        }
    }

    const float* qbase = Qbuf + (size_t)base * DMODEL + h * DHEAD;

    for (int r = w; r <= len; r += 4) {
        const float* qp = qbase + (size_t)r * DMODEL;
        float e0 = 0.f, e1 = 0.f, e2 = 0.f, e3 = 0.f;
        #pragma unroll
        for (int d = 0; d < 8; ++d) {
            float4 qv = *(const float4*)&qp[d * 4];
            e0 += qv.x * kc[0][d].x + qv.y * kc[0][d].y + qv.z * kc[0][d].z + qv.w * kc[0][d].w;
            e1 += qv.x * kc[1][d].x + qv.y * kc[1][d].y + qv.z * kc[1][d].z + qv.w * kc[1][d].w;
            e2 += qv.x * kc[2][d].x + qv.y * kc[2][d].y + qv.z * kc[2][d].z + qv.w * kc[2][d].w;
            e3 += qv.x * kc[3][d].x + qv.y * kc[3][d].y + qv.z * kc[3][d].z + qv.w * kc[3][d].w;
        }
        // column 256 participates only when len==256; lane 0 owns it (loads are rare+L1-hot)
        float e4 = -1e30f;
        if (len == 256 && l == 0) {
            const float* kp = Kbuf + (size_t)(base + 256) * DMODEL + h * DHEAD;
            float a = 0.f;
            #pragma unroll
            for (int d = 0; d < 8; ++d) {
                float4 qv = *(const float4*)&qp[d * 4];
                float4 kv = *(const float4*)&kp[d * 4];
                a += qv.x * kv.x + qv.y * kv.y + qv.z * kv.z + qv.w * kv.w;
            }
            e4 = a * SCALE;
        }
        e0 = (l       <= len) ? e0 * SCALE : -1e30f;
        e1 = (l +  64 <= len) ? e1 * SCALE : -1e30f;
        e2 = (l + 128 <= len) ? e2 * SCALE : -1e30f;
        e3 = (l + 192 <= len) ? e3 * SCALE : -1e30f;

        float m = fmaxf(fmaxf(e0, e1), fmaxf(e2, e3));
        m = fmaxf(m, e4);
        #pragma unroll
        for (int off = 1; off < 64; off <<= 1) m = fmaxf(m, __shfl_xor(m, off));

        float p0 = __expf(e0 - m), p1 = __expf(e1 - m);
        float p2 = __expf(e2 - m), p3 = __expf(e3 - m);
        float p4 = __expf(e4 - m);
        float s = p0 + p1 + p2 + p3 + p4;
        #pragma unroll
        for (int off = 1; off < 64; off <<= 1) s += __shfl_xor(s, off);
        float invs = 1.f / s;

        size_t ro = (size_t)r * LP1;
        out[ro + l      ] = p0 * invs;
        out[ro + l +  64] = p1 * invs;
        out[ro + l + 128] = p2 * invs;
        out[ro + l + 192] = p3 * invs;
        if (l == 0) out[ro + 256] = (len == 256) ? p4 * invs : 0.f;
    }

    // masked rows -> uniform 1/257, flat coalesced fill
    const float inv257 = 1.f / 257.f;
    for (size_t i = (size_t)(len + 1) * LP1 + t; i < (size_t)LP1 * LP1; i += 256) out[i] = inv257;
}

// ---------------- kernel 5: CLS readout ----------------
__global__ __launch_bounds__(256) void k_out(const float* __restrict__ x,
                                             const float* __restrict__ cls_emb,
                                             const float* __restrict__ Wv,
                                             const float* __restrict__ Wo,
                                             const int* __restrict__ lengths,
                                             const int* __restrict__ offsets,
                                             const float* __restrict__ alpha,
                                             float* __restrict__ cls_out) {
    int b = blockIdx.x, t = threadIdx.x;
    int len = lengths[b], off = offsets[b];

    __shared__ float aw[NHEAD][LP1];
    __shared__ float ctx[NHEAD][DMODEL];
    __shared__ float attnout[DMODEL];

    int L1 = len + 1;
    for (int i = t; i < NHEAD * L1; i += 256) {
        int h = i / L1, y = i - h * L1;
        aw[h][y] = alpha[((size_t)(b * NHEAD + h) * LP1 + len) * LP1 + y];
    }
    __syncthreads();

    float acc[NHEAD] = {};
    for (int y = 0; y < L1; ++y) {
        const float* src = (y < len) ? (x + (size_t)(off + y) * DMODEL) : cls_emb;
        float xv = src[t];
        #pragma unroll
        for (int h = 0; h < NHEAD; ++h) acc[h] += aw[h][y] * xv;
    }
    #pragma unroll
    for (int h = 0; h < NHEAD; ++h) ctx[h][t] = acc[h];
    __syncthreads();

    {
        int n = t, h = n >> 5;
        float s = 0.f;
        for (int c = 0; c < DMODEL; ++c) s += ctx[h][c] * Wv[(size_t)c * DMODEL + n];
        attnout[n] = s;
    }
    __syncthreads();

    {
        int n = t;
        float s = 0.f;
        for (int c = 0; c < DMODEL; ++c) s += attnout[c] * Wo[(size_t)c * DMODEL + n];
        cls_out[(size_t)b * DMODEL + n] = s;
    }
}

extern "C" void kernel_launch(void* const* d_in, const int* in_sizes, int n_in,
                              void* d_out, int out_size, void* d_ws, size_t ws_size,
                              hipStream_t stream) {
    const float* x       = (const float*)d_in[0];
    const int*   lengths = (const int*)d_in[1];
    const float* Wq      = (const float*)d_in[3];
    const float* Wk      = (const float*)d_in[4];
    const float* Wv      = (const float*)d_in[5];
    const float* Wo      = (const float*)d_in[6];
    const float* cls_emb = (const float*)d_in[7];

    int total = in_sizes[0] / DMODEL;
    int M = total + BATCH;
    int Mtiles = (M + 63) / 64;

    float* out     = (float*)d_out;
    float* cls_out = out;                        // [256,256]
    float* alpha   = out + BATCH * DMODEL;       // [256,8,257,257]

    char* wsb = (char*)d_ws;
    int* offsets   = (int*)wsb;
    int* valid_off = offsets + 256;
    int* src_idx   = valid_off + 256;
    size_t qoff = 2048 + (((size_t)M * 4 + 255) / 256) * 256;
    float* Qbuf = (float*)(wsb + qoff);
    size_t qsz  = (size_t)Mtiles * 64 * DMODEL * sizeof(float);
    float* Kbuf = (float*)(wsb + qoff + qsz);

    k_scan<<<1, 256, 0, stream>>>(lengths, offsets, valid_off);
    k_fill<<<BATCH, 256, 0, stream>>>(lengths, offsets, valid_off, src_idx);

    dim3 g2(Mtiles, 8);
    k_qk_gemm<<<g2, 256, 0, stream>>>(x, cls_emb, Wq, Wk, src_idx, M, Qbuf, Kbuf);

    dim3 g3(BATCH, NHEAD);
    k_attn<<<g3, 256, 0, stream>>>(Qbuf, Kbuf, lengths, valid_off, alpha);

    k_out<<<BATCH, 256, 0, stream>>>(x, cls_emb, Wv, Wo, lengths, offsets, alpha, cls_out);
}

// Round 4
// 642.004 us; speedup vs baseline: 1.6096x; 1.0573x over previous
//
#include <hip/hip_runtime.h>
#include <hip/hip_bf16.h>
#include <math.h>

#define BATCH 256
#define DMODEL 256
#define NHEAD 8
#define DHEAD 32
#define LP1 257
#define CH 9                         // ceil(257/32) row-chunks per (b,h)
#define SCALE 0.17677669529663687f   // 1/sqrt(32)

__device__ __forceinline__ float dot4(float4 a, float4 b) {
    return a.x * b.x + a.y * b.y + a.z * b.z + a.w * b.w;
}

// ---------------- kernel 1: scan lengths -> offsets, valid_off ----------------
__global__ __launch_bounds__(256) void k_scan(const int* __restrict__ lengths,
                                              int* __restrict__ offsets,
                                              int* __restrict__ valid_off) {
    __shared__ int s[BATCH];
    int t = threadIdx.x;
    int v = lengths[t];
    s[t] = v;
    __syncthreads();
    for (int d = 1; d < BATCH; d <<= 1) {
        int add = (t >= d) ? s[t - d] : 0;
        __syncthreads();
        s[t] += add;
        __syncthreads();
    }
    offsets[t]   = s[t] - v;          // exclusive cumsum of lengths
    valid_off[t] = s[t] - v + t;      // packed valid-row base (each batch adds 1 CLS)
}

// ---------------- kernel 2: fill src_idx over packed valid rows ----------------
__global__ __launch_bounds__(256) void k_fill(const int* __restrict__ lengths,
                                              const int* __restrict__ offsets,
                                              const int* __restrict__ valid_off,
                                              int* __restrict__ src_idx) {
    int b = blockIdx.x;
    int len = lengths[b], off = offsets[b], vo = valid_off[b];
    for (int p = threadIdx.x; p < len; p += blockDim.x) src_idx[vo + p] = off + p;
    if (threadIdx.x == 0) src_idx[vo + len] = -1;   // CLS marker
}

// ---------------- kernel 3: packed-row GEMM  [M,256] @ (Wq|Wk) -> Qbuf,Kbuf ----
__global__ __launch_bounds__(256) void k_qk_gemm(const float* __restrict__ x,
                                                 const float* __restrict__ cls_emb,
                                                 const float* __restrict__ Wq,
                                                 const float* __restrict__ Wk,
                                                 const int* __restrict__ src_idx,
                                                 int M,
                                                 float* __restrict__ Qbuf,
                                                 float* __restrict__ Kbuf) {
    int mt = blockIdx.x, nt = blockIdx.y;
    const float* W   = (nt < 4) ? Wq   : Wk;
    float*       Obf = (nt < 4) ? Qbuf : Kbuf;
    int col0 = (nt & 3) * 64;
    int r0   = mt * 64;

    __shared__ float As[64][65];
    __shared__ float Bs[64][68];

    int t  = threadIdx.x;
    int tx = t & 15, ty = t >> 4;
    float acc[4][4] = {};

    for (int kc = 0; kc < 256; kc += 64) {
        for (int i = t; i < 64 * 64; i += 256) {
            int rl = i >> 6, kl = i & 63;
            int r = r0 + rl;
            float v = 0.f;
            if (r < M) {
                int s = src_idx[r];
                const float* src = (s >= 0) ? (x + (size_t)s * DMODEL) : cls_emb;
                v = src[kc + kl];
            }
            As[rl][kl] = v;
        }
        for (int i = t; i < 64 * 64; i += 256) {
            int kl = i >> 6, nl = i & 63;
            Bs[kl][nl] = W[(size_t)(kc + kl) * DMODEL + col0 + nl];
        }
        __syncthreads();
        #pragma unroll 16
        for (int kk = 0; kk < 64; ++kk) {
            float a0 = As[ty * 4 + 0][kk];
            float a1 = As[ty * 4 + 1][kk];
            float a2 = As[ty * 4 + 2][kk];
            float a3 = As[ty * 4 + 3][kk];
            float4 bv = *(const float4*)&Bs[kk][tx * 4];
            acc[0][0] += a0 * bv.x; acc[0][1] += a0 * bv.y; acc[0][2] += a0 * bv.z; acc[0][3] += a0 * bv.w;
            acc[1][0] += a1 * bv.x; acc[1][1] += a1 * bv.y; acc[1][2] += a1 * bv.z; acc[1][3] += a1 * bv.w;
            acc[2][0] += a2 * bv.x; acc[2][1] += a2 * bv.y; acc[2][2] += a2 * bv.z; acc[2][3] += a2 * bv.w;
            acc[3][0] += a3 * bv.x; acc[3][1] += a3 * bv.y; acc[3][2] += a3 * bv.z; acc[3][3] += a3 * bv.w;
        }
        __syncthreads();
    }
    for (int i = 0; i < 4; ++i) {
        int r = r0 + ty * 4 + i;
        if (r < M) {
            float4 v = make_float4(acc[i][0], acc[i][1], acc[i][2], acc[i][3]);
            *(float4*)&Obf[(size_t)r * DMODEL + col0 + tx * 4] = v;
        }
    }
}

// ---------------- kernel 4: chunked per-(b,h) attention, single pass ----------------
// Block = 32-row chunk of one (b,h). Wave owns rows (2 at a time for ILP); lane owns
// 4 fixed K-columns (+ shared K[256]) in VGPRs. Butterfly allreduce for max/sum,
// interleaved across the 2 rows. Every alpha element computed exactly once.
__global__ __launch_bounds__(256, 2) void k_attn(const float* __restrict__ Qbuf,
                                                 const float* __restrict__ Kbuf,
                                                 const int* __restrict__ lengths,
                                                 const int* __restrict__ valid_off,
                                                 float* __restrict__ alpha) {
    int c = blockIdx.x, b = blockIdx.y, h = blockIdx.z;
    int len  = __builtin_amdgcn_readfirstlane(lengths[b]);
    int base = __builtin_amdgcn_readfirstlane(valid_off[b]);
    int t = threadIdx.x;
    int l = t & 63;          // lane within wave
    int w = t >> 6;          // wave id (0..3)
    int r0 = c * 32;
    float* out = alpha + (size_t)(b * NHEAD + h) * (size_t)(LP1 * LP1);
    const float inv257 = 1.f / 257.f;

    // ---- masked rows in this chunk: uniform 1/257, flat coalesced ----
    {
        int fs = max(r0, len + 1);
        int fe = min(r0 + 32, LP1);
        for (size_t i = (size_t)fs * LP1 + t; i < (size_t)fe * LP1; i += 256)
            __builtin_nontemporal_store(inv257, &out[i]);
    }
    if (r0 > len) return;

    // ---- lane's 4 K columns + shared K[256] into registers ----
    float4 kc[4][8];
    #pragma unroll
    for (int j = 0; j < 4; ++j) {
        #pragma unroll
        for (int d = 0; d < 8; ++d) kc[j][d] = make_float4(0.f, 0.f, 0.f, 0.f);
        int cc = l + 64 * j;
        if (cc <= len) {
            const float* kp = Kbuf + (size_t)(base + cc) * DMODEL + h * DHEAD;
            #pragma unroll
            for (int d = 0; d < 8; ++d) kc[j][d] = *(const float4*)&kp[d * 4];
        }
    }
    bool full = (len == 256);
    float4 k4[8];
    #pragma unroll
    for (int d = 0; d < 8; ++d) k4[d] = make_float4(0.f, 0.f, 0.f, 0.f);
    if (full) {
        const float* kp = Kbuf + (size_t)(base + 256) * DMODEL + h * DHEAD;
        #pragma unroll
        for (int d = 0; d < 8; ++d) k4[d] = *(const float4*)&kp[d * 4];
    }

    int rlast = min(len, r0 + 31);
    const float* qbase = Qbuf + (size_t)base * DMODEL + h * DHEAD;

    for (int r = r0 + w; r <= rlast; r += 8) {
        int rB = min(r + 4, rlast);
        bool hasB = (r + 4 <= rlast);              // wave-uniform
        const float* qpA = qbase + (size_t)r  * DMODEL;
        const float* qpB = qbase + (size_t)rB * DMODEL;

        float eA0 = 0.f, eA1 = 0.f, eA2 = 0.f, eA3 = 0.f, e4A = 0.f;
        float eB0 = 0.f, eB1 = 0.f, eB2 = 0.f, eB3 = 0.f, e4B = 0.f;
        #pragma unroll
        for (int d = 0; d < 8; ++d) {
            float4 qa = *(const float4*)&qpA[d * 4];
            float4 qb = *(const float4*)&qpB[d * 4];
            eA0 += dot4(qa, kc[0][d]); eA1 += dot4(qa, kc[1][d]);
            eA2 += dot4(qa, kc[2][d]); eA3 += dot4(qa, kc[3][d]);
            e4A += dot4(qa, k4[d]);
            eB0 += dot4(qb, kc[0][d]); eB1 += dot4(qb, kc[1][d]);
            eB2 += dot4(qb, kc[2][d]); eB3 += dot4(qb, kc[3][d]);
            e4B += dot4(qb, k4[d]);
        }
        eA0 = (l       <= len) ? eA0 * SCALE : -1e30f;
        eA1 = (l +  64 <= len) ? eA1 * SCALE : -1e30f;
        eA2 = (l + 128 <= len) ? eA2 * SCALE : -1e30f;
        eA3 = (l + 192 <= len) ? eA3 * SCALE : -1e30f;
        e4A = full ? e4A * SCALE : -1e30f;
        eB0 = (l       <= len) ? eB0 * SCALE : -1e30f;
        eB1 = (l +  64 <= len) ? eB1 * SCALE : -1e30f;
        eB2 = (l + 128 <= len) ? eB2 * SCALE : -1e30f;
        eB3 = (l + 192 <= len) ? eB3 * SCALE : -1e30f;
        e4B = full ? e4B * SCALE : -1e30f;

        float mA = fmaxf(fmaxf(fmaxf(eA0, eA1), fmaxf(eA2, eA3)), e4A);
        float mB = fmaxf(fmaxf(fmaxf(eB0, eB1), fmaxf(eB2, eB3)), e4B);
        #pragma unroll
        for (int off = 1; off < 64; off <<= 1) {
            mA = fmaxf(mA, __shfl_xor(mA, off));
            mB = fmaxf(mB, __shfl_xor(mB, off));
        }

        float pA0 = __expf(eA0 - mA), pA1 = __expf(eA1 - mA);
        float pA2 = __expf(eA2 - mA), pA3 = __expf(eA3 - mA);
        float p4A = (l == 0) ? __expf(e4A - mA) : 0.f;
        float pB0 = __expf(eB0 - mB), pB1 = __expf(eB1 - mB);
        float pB2 = __expf(eB2 - mB), pB3 = __expf(eB3 - mB);
        float p4B = (l == 0) ? __expf(e4B - mB) : 0.f;

        float sA = pA0 + pA1 + pA2 + pA3 + p4A;
        float sB = pB0 + pB1 + pB2 + pB3 + p4B;
        #pragma unroll
        for (int off = 1; off < 64; off <<= 1) {
            sA += __shfl_xor(sA, off);
            sB += __shfl_xor(sB, off);
        }
        float invsA = 1.f / sA;
        float invsB = 1.f / sB;

        size_t roA = (size_t)r * LP1;
        __builtin_nontemporal_store(pA0 * invsA, &out[roA + l      ]);
        __builtin_nontemporal_store(pA1 * invsA, &out[roA + l +  64]);
        __builtin_nontemporal_store(pA2 * invsA, &out[roA + l + 128]);
        __builtin_nontemporal_store(pA3 * invsA, &out[roA + l + 192]);
        if (l == 0) __builtin_nontemporal_store(p4A * invsA, &out[roA + 256]);
        if (hasB) {
            size_t roB = (size_t)rB * LP1;
            __builtin_nontemporal_store(pB0 * invsB, &out[roB + l      ]);
            __builtin_nontemporal_store(pB1 * invsB, &out[roB + l +  64]);
            __builtin_nontemporal_store(pB2 * invsB, &out[roB + l + 128]);
            __builtin_nontemporal_store(pB3 * invsB, &out[roB + l + 192]);
            if (l == 0) __builtin_nontemporal_store(p4B * invsB, &out[roB + 256]);
        }
    }
}

// ---------------- kernel 5: CLS readout ----------------
__global__ __launch_bounds__(256) void k_out(const float* __restrict__ x,
                                             const float* __restrict__ cls_emb,
                                             const float* __restrict__ Wv,
                                             const float* __restrict__ Wo,
                                             const int* __restrict__ lengths,
                                             const int* __restrict__ offsets,
                                             const float* __restrict__ alpha,
                                             float* __restrict__ cls_out) {
    int b = blockIdx.x, t = threadIdx.x;
    int len = lengths[b], off = offsets[b];

    __shared__ float aw[NHEAD][LP1];
    __shared__ float ctx[NHEAD][DMODEL];
    __shared__ float attnout[DMODEL];

    int L1 = len + 1;
    for (int i = t; i < NHEAD * L1; i += 256) {
        int h = i / L1, y = i - h * L1;
        aw[h][y] = alpha[((size_t)(b * NHEAD + h) * LP1 + len) * LP1 + y];
    }
    __syncthreads();

    float acc[NHEAD] = {};
    for (int y = 0; y < L1; ++y) {
        const float* src = (y < len) ? (x + (size_t)(off + y) * DMODEL) : cls_emb;
        float xv = src[t];
        #pragma unroll
        for (int h = 0; h < NHEAD; ++h) acc[h] += aw[h][y] * xv;
    }
    #pragma unroll
    for (int h = 0; h < NHEAD; ++h) ctx[h][t] = acc[h];
    __syncthreads();

    {
        int n = t, h = n >> 5;
        float s = 0.f;
        for (int c = 0; c < DMODEL; ++c) s += ctx[h][c] * Wv[(size_t)c * DMODEL + n];
        attnout[n] = s;
    }
    __syncthreads();

    {
        int n = t;
        float s = 0.f;
        for (int c = 0; c < DMODEL; ++c) s += attnout[c] * Wo[(size_t)c * DMODEL + n];
        cls_out[(size_t)b * DMODEL + n] = s;
    }
}

extern "C" void kernel_launch(void* const* d_in, const int* in_sizes, int n_in,
                              void* d_out, int out_size, void* d_ws, size_t ws_size,
                              hipStream_t stream) {
    const float* x       = (const float*)d_in[0];
    const int*   lengths = (const int*)d_in[1];
    const float* Wq      = (const float*)d_in[3];
    const float* Wk      = (const float*)d_in[4];
    const float* Wv      = (const float*)d_in[5];
    const float* Wo      = (const float*)d_in[6];
    const float* cls_emb = (const float*)d_in[7];

    int total = in_sizes[0] / DMODEL;
    int M = total + BATCH;
    int Mtiles = (M + 63) / 64;

    float* out     = (float*)d_out;
    float* cls_out = out;                        // [256,256]
    float* alpha   = out + BATCH * DMODEL;       // [256,8,257,257]

    char* wsb = (char*)d_ws;
    int* offsets   = (int*)wsb;
    int* valid_off = offsets + 256;
    int* src_idx   = valid_off + 256;
    size_t qoff = 2048 + (((size_t)M * 4 + 255) / 256) * 256;
    float* Qbuf = (float*)(wsb + qoff);
    size_t qsz  = (size_t)Mtiles * 64 * DMODEL * sizeof(float);
    float* Kbuf = (float*)(wsb + qoff + qsz);

    k_scan<<<1, 256, 0, stream>>>(lengths, offsets, valid_off);
    k_fill<<<BATCH, 256, 0, stream>>>(lengths, offsets, valid_off, src_idx);

    dim3 g2(Mtiles, 8);
    k_qk_gemm<<<g2, 256, 0, stream>>>(x, cls_emb, Wq, Wk, src_idx, M, Qbuf, Kbuf);

    dim3 g3(CH, BATCH, NHEAD);
    k_attn<<<g3, 256, 0, stream>>>(Qbuf, Kbuf, lengths, valid_off, alpha);

    k_out<<<BATCH, 256, 0, stream>>>(x, cls_emb, Wv, Wo, lengths, offsets, alpha, cls_out);
}